// Round 2
// baseline (1090.781 us; speedup 1.0000x reference)
//
#include <hip/hip_runtime.h>

#define D 64
#define K 1024
#define NROWS (32 * 4096)
#define NELEM (NROWS * D)
#define COMMIT 0.25f

// Opaque-value fence: prevents mul+add contraction across it so we can
// reproduce numpy's exact f32 rounding sequence (fl(x*x) then separate adds).
static __device__ __forceinline__ float fence(float v) {
    asm("" : "+v"(v));
    return v;
}

// numpy pairwise_sum for n=64: 8 accumulators stride 8, sequential block
// adds, then ((r0+r1)+(r2+r3)) + ((r4+r5)+(r6+r7)).
static __device__ __forceinline__ float np_sumsq64(const float* __restrict__ e) {
    float r[8];
#pragma unroll
    for (int j = 0; j < 8; ++j) r[j] = fence(e[j] * e[j]);
#pragma unroll
    for (int t = 1; t < 8; ++t)
#pragma unroll
        for (int j = 0; j < 8; ++j) r[j] = r[j] + fence(e[8 * t + j] * e[8 * t + j]);
    return ((r[0] + r[1]) + (r[2] + r[3])) + ((r[4] + r[5]) + (r[6] + r[7]));
}

// ---------------- Kernel 1: embedding norms + zero loss slot ----------------
__global__ void enorm_kernel(const float* __restrict__ emb,
                             float* __restrict__ enorm,
                             float* __restrict__ loss_slot) {
    int k = blockIdx.x * blockDim.x + threadIdx.x;
    if (k == 0) *loss_slot = 0.0f;
    if (k < K) enorm[k] = np_sumsq64(emb + k * D);
}

// ---------------- Kernel 2: per-row argmin over K codes ----------------
// Replicates the reference's f32 computation bit-for-bit:
//   dist_k = fl( fl(rownorm + enorm_k) - 2*dot_k )
// rownorm via numpy pairwise order; dot via sequential-k FMA chain (the
// order OpenBLAS/Eigen sgemm use). The ulp(rownorm~64) binning makes
// near-ties EXACT ties, resolved by first index (strict <), matching
// np.argmin.
__global__ __launch_bounds__(256) void argmin_kernel(
    const float* __restrict__ x, const float* __restrict__ emb,
    const float* __restrict__ enorm, int* __restrict__ idx_i,
    float* __restrict__ idx_f) {
    int row = blockIdx.x * 256 + threadIdx.x;
    float xe[D];
    const float4* xr = (const float4*)(x + (size_t)row * D);
#pragma unroll
    for (int i = 0; i < D / 4; ++i) {
        float4 v = xr[i];
        xe[4 * i + 0] = v.x;
        xe[4 * i + 1] = v.y;
        xe[4 * i + 2] = v.z;
        xe[4 * i + 3] = v.w;
    }
    float R = np_sumsq64(xe);

    float best = 3.402823466e+38f;
    int bidx = 0;
#pragma unroll 2
    for (int k = 0; k < K; ++k) {
        const float* __restrict__ e = emb + (k << 6);  // wave-uniform row
        float acc = 0.0f;
#pragma unroll
        for (int i = 0; i < D; ++i) acc = __builtin_fmaf(xe[i], e[i], acc);
        float s = (R + enorm[k]) - 2.0f * acc;  // final rounding at ulp(R)
        if (s < best) {  // strict <: first occurrence wins, like np.argmin
            best = s;
            bidx = k;
        }
    }
    idx_i[row] = bidx;
    idx_f[row] = (float)bidx;  // harness reads d_out as f32
}

// ---------------- Kernel 3: gather + straight-through + loss ----------------
__global__ __launch_bounds__(256) void quant_loss_kernel(
    const float* __restrict__ x, const float* __restrict__ emb,
    const int* __restrict__ idx, float* __restrict__ out_q,
    float* __restrict__ loss_slot) {
    int j = blockIdx.x * 256 + threadIdx.x;  // one element per thread
    int row = j >> 6;
    int d = j & 63;
    int k = idx[row];
    float xv = x[j];
    float ev = emb[(k << 6) + d];
    float diff = ev - xv;              // stop_gradient(quantized - inputs)
    out_q[j] = xv + diff;              // inputs + (quantized - inputs)
    float lsum = diff * diff;

#pragma unroll
    for (int o = 32; o > 0; o >>= 1) lsum += __shfl_xor(lsum, o);
    __shared__ float wsum[4];
    int wid = threadIdx.x >> 6;
    if ((threadIdx.x & 63) == 0) wsum[wid] = lsum;
    __syncthreads();
    if (threadIdx.x == 0) {
        float bsum = (wsum[0] + wsum[1]) + (wsum[2] + wsum[3]);
        // loss = (1 + commitment_cost) * mean(diff^2)
        atomicAdd(loss_slot, bsum * ((1.0f + COMMIT) / (float)NELEM));
    }
}

extern "C" void kernel_launch(void* const* d_in, const int* in_sizes, int n_in,
                              void* d_out, int out_size, void* d_ws,
                              size_t ws_size, hipStream_t stream) {
    const float* x = (const float*)d_in[0];    // [32,4096,64] f32
    const float* emb = (const float*)d_in[1];  // [1024,64] f32

    float* out = (float*)d_out;
    float* loss_slot = out;              // out[0]
    float* out_q = out + 1;              // out[1 .. 1+NELEM)
    float* idx_f = out + 1 + NELEM;      // indices as f32

    float* enorm = (float*)d_ws;                 // 4 KB
    int* idx_i = (int*)((char*)d_ws + 4096);     // 512 KB

    enorm_kernel<<<(K + 255) / 256, 256, 0, stream>>>(emb, enorm, loss_slot);
    argmin_kernel<<<NROWS / 256, 256, 0, stream>>>(x, emb, enorm, idx_i,
                                                   idx_f);
    quant_loss_kernel<<<NELEM / 256, 256, 0, stream>>>(x, emb, idx_i, out_q,
                                                       loss_slot);
}

// Round 3
// 974.438 us; speedup vs baseline: 1.1194x; 1.1194x over previous
//
#include <hip/hip_runtime.h>

#define D 64
#define K 1024
#define NROWS (32 * 4096)
#define NELEM (NROWS * D)
#define COMMIT 0.25f
#define QBLOCKS 2048

// Opaque-value fence: prevents mul+add contraction so we can reproduce
// numpy's exact f32 rounding sequence (fl(x*x) then separate adds).
static __device__ __forceinline__ float fence(float v) {
    asm("" : "+v"(v));
    return v;
}

// numpy pairwise_sum for n=64: 8 accumulators stride 8, sequential block
// adds, then ((r0+r1)+(r2+r3)) + ((r4+r5)+(r6+r7)).
static __device__ __forceinline__ float np_sumsq64(const float* __restrict__ e) {
    float r[8];
#pragma unroll
    for (int j = 0; j < 8; ++j) r[j] = fence(e[j] * e[j]);
#pragma unroll
    for (int t = 1; t < 8; ++t)
#pragma unroll
        for (int j = 0; j < 8; ++j) r[j] = r[j] + fence(e[8 * t + j] * e[8 * t + j]);
    return ((r[0] + r[1]) + (r[2] + r[3])) + ((r[4] + r[5]) + (r[6] + r[7]));
}

// ---------------- Kernel 1: embedding norms + zero loss slot ----------------
__global__ void enorm_kernel(const float* __restrict__ emb,
                             float* __restrict__ enorm,
                             float* __restrict__ loss_slot) {
    int k = blockIdx.x * blockDim.x + threadIdx.x;
    if (k == 0) *loss_slot = 0.0f;
    if (k < K) enorm[k] = np_sumsq64(emb + k * D);
}

// ---------------- Kernel 2: per-row argmin, K-split x4, ILP x4 ----------------
// Same bit-exact score as the passing R2 kernel:
//   s_k = fl( fl(R + enorm_k) - 2*dot_k ),  dot via sequential-i FMA chain.
// Block = 256 threads = 4 waves; wave w scans codes [256w, 256w+256) for the
// same 64 rows. Cross-wave combine in ascending-k order with strict < keeps
// numpy's first-index tiebreak globally.
__global__ __launch_bounds__(256) void argmin_kernel(
    const float* __restrict__ x, const float* __restrict__ emb,
    const float* __restrict__ enorm, int* __restrict__ idx_i,
    float* __restrict__ idx_f) {
    __shared__ float sbest[4][64];
    __shared__ int sidx[4][64];
    const int w = threadIdx.x >> 6;
    const int l = threadIdx.x & 63;
    const int row = blockIdx.x * 64 + l;

    float xe[D];
    const float4* xr = (const float4*)(x + (size_t)row * D);
#pragma unroll
    for (int i = 0; i < D / 4; ++i) {
        float4 v = xr[i];
        xe[4 * i + 0] = v.x;
        xe[4 * i + 1] = v.y;
        xe[4 * i + 2] = v.z;
        xe[4 * i + 3] = v.w;
    }
    const float R = np_sumsq64(xe);  // identical in all 4 waves

    const int k0 = w * 256;
    float best = 3.402823466e+38f;
    int bidx = k0;
    for (int k = k0; k < k0 + 256; k += 4) {
        const float* __restrict__ e = emb + (k << 6);  // wave-uniform
        float a0 = 0.f, a1 = 0.f, a2 = 0.f, a3 = 0.f;
#pragma unroll
        for (int i = 0; i < D; ++i) {
            a0 = __builtin_fmaf(xe[i], e[i], a0);
            a1 = __builtin_fmaf(xe[i], e[64 + i], a1);
            a2 = __builtin_fmaf(xe[i], e[128 + i], a2);
            a3 = __builtin_fmaf(xe[i], e[192 + i], a3);
        }
        float s0 = (R + enorm[k + 0]) - 2.0f * a0;
        float s1 = (R + enorm[k + 1]) - 2.0f * a1;
        float s2 = (R + enorm[k + 2]) - 2.0f * a2;
        float s3 = (R + enorm[k + 3]) - 2.0f * a3;
        if (s0 < best) { best = s0; bidx = k + 0; }
        if (s1 < best) { best = s1; bidx = k + 1; }
        if (s2 < best) { best = s2; bidx = k + 2; }
        if (s3 < best) { best = s3; bidx = k + 3; }
    }
    sbest[w][l] = best;
    sidx[w][l] = bidx;
    __syncthreads();
    if (w == 0) {
        float b = sbest[0][l];
        int bi = sidx[0][l];
#pragma unroll
        for (int ww = 1; ww < 4; ++ww) {  // ascending k: strict < = first index
            float c = sbest[ww][l];
            if (c < b) { b = c; bi = sidx[ww][l]; }
        }
        idx_i[row] = bi;
        idx_f[row] = (float)bi;
    }
}

// ---------------- Kernel 3: gather + straight-through + loss ----------------
// Grid-stride, one atomic per block (2048 total, was 32768).
__global__ __launch_bounds__(256) void quant_loss_kernel(
    const float* __restrict__ x, const float* __restrict__ emb,
    const int* __restrict__ idx, float* __restrict__ out_q,
    float* __restrict__ loss_slot) {
    float lsum = 0.0f;
    for (int j = blockIdx.x * 256 + threadIdx.x; j < NELEM;
         j += QBLOCKS * 256) {
        int row = j >> 6;
        int d = j & 63;
        int k = idx[row];
        float xv = x[j];
        float ev = emb[(k << 6) + d];
        float diff = ev - xv;   // stop_gradient(quantized - inputs)
        out_q[j] = xv + diff;   // inputs + (quantized - inputs)
        lsum = __builtin_fmaf(diff, diff, lsum);
    }
#pragma unroll
    for (int o = 32; o > 0; o >>= 1) lsum += __shfl_xor(lsum, o);
    __shared__ float wsum[4];
    int wid = threadIdx.x >> 6;
    if ((threadIdx.x & 63) == 0) wsum[wid] = lsum;
    __syncthreads();
    if (threadIdx.x == 0) {
        float bsum = (wsum[0] + wsum[1]) + (wsum[2] + wsum[3]);
        // loss = (1 + commitment_cost) * mean(diff^2)
        atomicAdd(loss_slot, bsum * ((1.0f + COMMIT) / (float)NELEM));
    }
}

extern "C" void kernel_launch(void* const* d_in, const int* in_sizes, int n_in,
                              void* d_out, int out_size, void* d_ws,
                              size_t ws_size, hipStream_t stream) {
    const float* x = (const float*)d_in[0];    // [32,4096,64] f32
    const float* emb = (const float*)d_in[1];  // [1024,64] f32

    float* out = (float*)d_out;
    float* loss_slot = out;              // out[0]
    float* out_q = out + 1;              // out[1 .. 1+NELEM)
    float* idx_f = out + 1 + NELEM;      // indices as f32

    float* enorm = (float*)d_ws;                 // 4 KB
    int* idx_i = (int*)((char*)d_ws + 4096);     // 512 KB

    enorm_kernel<<<(K + 255) / 256, 256, 0, stream>>>(emb, enorm, loss_slot);
    argmin_kernel<<<NROWS / 64, 256, 0, stream>>>(x, emb, enorm, idx_i, idx_f);
    quant_loss_kernel<<<QBLOCKS, 256, 0, stream>>>(x, emb, idx_i, out_q,
                                                   loss_slot);
}

// Round 4
// 656.865 us; speedup vs baseline: 1.6606x; 1.4835x over previous
//
#include <hip/hip_runtime.h>

#define D 64
#define K 1024
#define NROWS (32 * 4096)
#define NELEM (NROWS * D)
#define COMMIT 0.25f
#define QBLOCKS 2048

// Opaque-value fence: prevents mul+add contraction so we can reproduce
// numpy's exact f32 rounding sequence (fl(x*x) then separate adds).
static __device__ __forceinline__ float fence(float v) {
    asm("" : "+v"(v));
    return v;
}

// numpy pairwise_sum for n=64: 8 accumulators stride 8, sequential block
// adds, then ((r0+r1)+(r2+r3)) + ((r4+r5)+(r6+r7)).
static __device__ __forceinline__ float np_sumsq64(const float* __restrict__ e) {
    float r[8];
#pragma unroll
    for (int j = 0; j < 8; ++j) r[j] = fence(e[j] * e[j]);
#pragma unroll
    for (int t = 1; t < 8; ++t)
#pragma unroll
        for (int j = 0; j < 8; ++j) r[j] = r[j] + fence(e[8 * t + j] * e[8 * t + j]);
    return ((r[0] + r[1]) + (r[2] + r[3])) + ((r[4] + r[5]) + (r[6] + r[7]));
}

// ---------------- Kernel 1: embedding norms + zero loss slot ----------------
__global__ void enorm_kernel(const float* __restrict__ emb,
                             float* __restrict__ enorm,
                             float* __restrict__ loss_slot) {
    int k = blockIdx.x * blockDim.x + threadIdx.x;
    if (k == 0) *loss_slot = 0.0f;
    if (k < K) enorm[k] = np_sumsq64(emb + k * D);
}

// ---------------- Kernel 2: per-row argmin, xe-in-VGPR, dual FMA chains ----
// Bit-exact score (same as passing R2/R3 kernels):
//   s_k = fl( fl(R + enorm_k) - 2*dot_k ),  dot = sequential-i FMA chain.
// __launch_bounds__(256, 1): allow max VGPRs so xe[64] stays register-
// resident (R2/R3 counters showed VGPR=40/52 -> xe was spilled; that, not
// issue rate, was the bottleneck). K-unroll of exactly 2: two independent
// chains cover the 4-cyc FMA latency at 2-cyc issue, while 2 embedding rows
// still fit the scalar (s_load) operand path that R2's SGPR=112 proved works.
__global__ __launch_bounds__(256, 1) void argmin_kernel(
    const float* __restrict__ x, const float* __restrict__ emb,
    const float* __restrict__ enorm, int* __restrict__ idx_i,
    float* __restrict__ idx_f) {
    const int row = blockIdx.x * 256 + threadIdx.x;
    float xe[D];
    const float4* xr = (const float4*)(x + (size_t)row * D);
#pragma unroll
    for (int i = 0; i < D / 4; ++i) {
        float4 v = xr[i];
        xe[4 * i + 0] = v.x;
        xe[4 * i + 1] = v.y;
        xe[4 * i + 2] = v.z;
        xe[4 * i + 3] = v.w;
    }
    const float R = np_sumsq64(xe);

    float best = 3.402823466e+38f;
    int bidx = 0;
    for (int k = 0; k < K; k += 2) {
        const float* __restrict__ e0 = emb + (k << 6);  // wave-uniform
        const float* __restrict__ e1 = e0 + D;
        float a0 = 0.0f, a1 = 0.0f;
#pragma unroll
        for (int i = 0; i < D; ++i) {
            a0 = __builtin_fmaf(xe[i], e0[i], a0);
            a1 = __builtin_fmaf(xe[i], e1[i], a1);
        }
        float s0 = (R + enorm[k + 0]) - 2.0f * a0;
        float s1 = (R + enorm[k + 1]) - 2.0f * a1;
        if (s0 < best) { best = s0; bidx = k + 0; }  // strict <: first index
        if (s1 < best) { best = s1; bidx = k + 1; }
    }
    idx_i[row] = bidx;
    idx_f[row] = (float)bidx;  // harness reads d_out as f32
}

// ---------------- Kernel 3: gather + straight-through + loss ----------------
// Grid-stride, one atomic per block.
__global__ __launch_bounds__(256) void quant_loss_kernel(
    const float* __restrict__ x, const float* __restrict__ emb,
    const int* __restrict__ idx, float* __restrict__ out_q,
    float* __restrict__ loss_slot) {
    float lsum = 0.0f;
    for (int j = blockIdx.x * 256 + threadIdx.x; j < NELEM;
         j += QBLOCKS * 256) {
        int row = j >> 6;
        int d = j & 63;
        int k = idx[row];
        float xv = x[j];
        float ev = emb[(k << 6) + d];
        float diff = ev - xv;   // stop_gradient(quantized - inputs)
        out_q[j] = xv + diff;   // inputs + (quantized - inputs)
        lsum = __builtin_fmaf(diff, diff, lsum);
    }
#pragma unroll
    for (int o = 32; o > 0; o >>= 1) lsum += __shfl_xor(lsum, o);
    __shared__ float wsum[4];
    int wid = threadIdx.x >> 6;
    if ((threadIdx.x & 63) == 0) wsum[wid] = lsum;
    __syncthreads();
    if (threadIdx.x == 0) {
        float bsum = (wsum[0] + wsum[1]) + (wsum[2] + wsum[3]);
        // loss = (1 + commitment_cost) * mean(diff^2)
        atomicAdd(loss_slot, bsum * ((1.0f + COMMIT) / (float)NELEM));
    }
}

extern "C" void kernel_launch(void* const* d_in, const int* in_sizes, int n_in,
                              void* d_out, int out_size, void* d_ws,
                              size_t ws_size, hipStream_t stream) {
    const float* x = (const float*)d_in[0];    // [32,4096,64] f32
    const float* emb = (const float*)d_in[1];  // [1024,64] f32

    float* out = (float*)d_out;
    float* loss_slot = out;              // out[0]
    float* out_q = out + 1;              // out[1 .. 1+NELEM)
    float* idx_f = out + 1 + NELEM;      // indices as f32

    float* enorm = (float*)d_ws;                 // 4 KB
    int* idx_i = (int*)((char*)d_ws + 4096);     // 512 KB

    enorm_kernel<<<(K + 255) / 256, 256, 0, stream>>>(emb, enorm, loss_slot);
    argmin_kernel<<<NROWS / 256, 256, 0, stream>>>(x, emb, enorm, idx_i,
                                                   idx_f);
    quant_loss_kernel<<<QBLOCKS, 256, 0, stream>>>(x, emb, idx_i, out_q,
                                                   loss_slot);
}

// Round 6
// 654.703 us; speedup vs baseline: 1.6661x; 1.0033x over previous
//
#include <hip/hip_runtime.h>

#define D 64
#define K 1024
#define NROWS (32 * 4096)
#define NELEM (NROWS * D)
#define COMMIT 0.25f
#define QBLOCKS 2048

// Opaque-value fence: prevents mul+add contraction so we can reproduce
// numpy's exact f32 rounding sequence (fl(x*x) then separate adds).
static __device__ __forceinline__ float fence(float v) {
    asm("" : "+v"(v));
    return v;
}

// numpy pairwise_sum for n=64: 8 accumulators stride 8, sequential block
// adds, then ((r0+r1)+(r2+r3)) + ((r4+r5)+(r6+r7)).
static __device__ __forceinline__ float np_sumsq64(const float* __restrict__ e) {
    float r[8];
#pragma unroll
    for (int j = 0; j < 8; ++j) r[j] = fence(e[j] * e[j]);
#pragma unroll
    for (int t = 1; t < 8; ++t)
#pragma unroll
        for (int j = 0; j < 8; ++j) r[j] = r[j] + fence(e[8 * t + j] * e[8 * t + j]);
    return ((r[0] + r[1]) + (r[2] + r[3])) + ((r[4] + r[5]) + (r[6] + r[7]));
}

// ---------------- Kernel 1: embedding norms + zero loss slot ----------------
__global__ void enorm_kernel(const float* __restrict__ emb,
                             float* __restrict__ enorm,
                             float* __restrict__ loss_slot) {
    int k = blockIdx.x * blockDim.x + threadIdx.x;
    if (k == 0) *loss_slot = 0.0f;
    if (k < K) enorm[k] = np_sumsq64(emb + k * D);
}

// ---------------- Kernel 2: per-row argmin, register-pinned x ----------------
// Bit-exact score (same chain as the passing R2/R3/R4 kernels):
//   s_k = fl( fl(R + enorm_k) - 2*dot_k ),  dot = sequential-i FMA chain,
//   R = numpy pairwise sumsq. Strict < in ascending k = first-index tiebreak.
// R2/R4 counters (VGPR=40) showed the compiler re-loads x from global inside
// the k-loop instead of keeping it resident. Per-iteration SCALAR asm pins
// (tied float4 operands don't compile) make re-loading illegal: x must live
// in 64 VGPRs.
__global__ __launch_bounds__(256, 1) void argmin_kernel(
    const float* __restrict__ x, const float* __restrict__ emb,
    const float* __restrict__ enorm, int* __restrict__ idx_i,
    float* __restrict__ idx_f) {
    const int row = blockIdx.x * 256 + threadIdx.x;
    const float4* __restrict__ xr = (const float4*)(x + (size_t)row * D);
    float xe[D];
#pragma unroll
    for (int i = 0; i < 16; ++i) {
        float4 v = xr[i];
        xe[4 * i + 0] = v.x;
        xe[4 * i + 1] = v.y;
        xe[4 * i + 2] = v.z;
        xe[4 * i + 3] = v.w;
    }
    const float R = np_sumsq64(xe);

    float best = 3.402823466e+38f;
    int bidx = 0;
    for (int k = 0; k < K; k += 2) {
#pragma unroll
        for (int i = 0; i < D; ++i) asm("" : "+v"(xe[i]));  // pin x in VGPRs
        const float* __restrict__ e0 = emb + (k << 6);  // wave-uniform
        const float* __restrict__ e1 = e0 + D;
        float a0 = 0.0f, a1 = 0.0f;
#pragma unroll
        for (int i = 0; i < D; ++i) {
            a0 = __builtin_fmaf(xe[i], e0[i], a0);
            a1 = __builtin_fmaf(xe[i], e1[i], a1);
        }
        float s0 = (R + enorm[k + 0]) - 2.0f * a0;
        float s1 = (R + enorm[k + 1]) - 2.0f * a1;
        if (s0 < best) { best = s0; bidx = k + 0; }  // strict <: first index
        if (s1 < best) { best = s1; bidx = k + 1; }
    }
    idx_i[row] = bidx;
    idx_f[row] = (float)bidx;  // harness reads d_out as f32
}

// ---------------- Kernel 3: gather + straight-through + loss ----------------
__global__ __launch_bounds__(256) void quant_loss_kernel(
    const float* __restrict__ x, const float* __restrict__ emb,
    const int* __restrict__ idx, float* __restrict__ out_q,
    float* __restrict__ loss_slot) {
    float lsum = 0.0f;
    for (int j = blockIdx.x * 256 + threadIdx.x; j < NELEM;
         j += QBLOCKS * 256) {
        int row = j >> 6;
        int d = j & 63;
        int k = idx[row];
        float xv = x[j];
        float ev = emb[(k << 6) + d];
        float diff = ev - xv;   // stop_gradient(quantized - inputs)
        out_q[j] = xv + diff;   // inputs + (quantized - inputs)
        lsum = __builtin_fmaf(diff, diff, lsum);
    }
#pragma unroll
    for (int o = 32; o > 0; o >>= 1) lsum += __shfl_xor(lsum, o);
    __shared__ float wsum[4];
    int wid = threadIdx.x >> 6;
    if ((threadIdx.x & 63) == 0) wsum[wid] = lsum;
    __syncthreads();
    if (threadIdx.x == 0) {
        float bsum = (wsum[0] + wsum[1]) + (wsum[2] + wsum[3]);
        // loss = (1 + commitment_cost) * mean(diff^2)
        atomicAdd(loss_slot, bsum * ((1.0f + COMMIT) / (float)NELEM));
    }
}

extern "C" void kernel_launch(void* const* d_in, const int* in_sizes, int n_in,
                              void* d_out, int out_size, void* d_ws,
                              size_t ws_size, hipStream_t stream) {
    const float* x = (const float*)d_in[0];    // [32,4096,64] f32
    const float* emb = (const float*)d_in[1];  // [1024,64] f32

    float* out = (float*)d_out;
    float* loss_slot = out;              // out[0]
    float* out_q = out + 1;              // out[1 .. 1+NELEM)
    float* idx_f = out + 1 + NELEM;      // indices as f32

    float* enorm = (float*)d_ws;                 // 4 KB
    int* idx_i = (int*)((char*)d_ws + 4096);     // 512 KB

    enorm_kernel<<<(K + 255) / 256, 256, 0, stream>>>(emb, enorm, loss_slot);
    argmin_kernel<<<NROWS / 256, 256, 0, stream>>>(x, emb, enorm, idx_i,
                                                   idx_f);
    quant_loss_kernel<<<QBLOCKS, 256, 0, stream>>>(x, emb, idx_i, out_q,
                                                   loss_slot);
}

// Round 7
// 465.450 us; speedup vs baseline: 2.3435x; 1.4066x over previous
//
#include <hip/hip_runtime.h>

#define D 64
#define K 1024
#define NROWS (32 * 4096)
#define NELEM (NROWS * D)
#define COMMIT 0.25f
#define QBLOCKS 4096

// Opaque-value fence: prevents mul+add contraction so we can reproduce
// numpy's exact f32 rounding sequence (fl(x*x) then separate adds).
static __device__ __forceinline__ float fence(float v) {
    asm("" : "+v"(v));
    return v;
}

// Real identity mov: result of an asm can never be rematerialized, so the
// value is forced to stay in a VGPR across enclosing loops. (Empty tied-asm
// pins get coalesced away -- R6 lesson.)
static __device__ __forceinline__ float vpin(float v) {
    float o;
    asm("v_mov_b32 %0, %1" : "=v"(o) : "v"(v));
    return o;
}

// numpy pairwise_sum for n=64: 8 accumulators stride 8, sequential block
// adds, then ((r0+r1)+(r2+r3)) + ((r4+r5)+(r6+r7)).
static __device__ __forceinline__ float np_sumsq64(const float* __restrict__ e) {
    float r[8];
#pragma unroll
    for (int j = 0; j < 8; ++j) r[j] = fence(e[j] * e[j]);
#pragma unroll
    for (int t = 1; t < 8; ++t)
#pragma unroll
        for (int j = 0; j < 8; ++j) r[j] = r[j] + fence(e[8 * t + j] * e[8 * t + j]);
    return ((r[0] + r[1]) + (r[2] + r[3])) + ((r[4] + r[5]) + (r[6] + r[7]));
}

// ---------------- Kernel 1: embedding norms + zero loss slot ----------------
__global__ void enorm_kernel(const float* __restrict__ emb,
                             float* __restrict__ enorm,
                             float* __restrict__ loss_slot) {
    int k = blockIdx.x * blockDim.x + threadIdx.x;
    if (k == 0) *loss_slot = 0.0f;
    if (k < K) enorm[k] = np_sumsq64(emb + k * D);
}

// ---------------- Kernel 2: role-swapped argmin ----------------
// Lane l owns codes {gp*128+l, gp*128+64+l}; their embedding rows live in
// 128 pinned VGPRs, reloaded once per 64 rows. The x-row is wave-uniform ->
// scalar s_loads feed v_fma directly (1 SGPR operand per FMA, no per-FMA
// memory traffic). Scores are bit-identical to the reference chain:
//   s_k = fl( fl(R + N_k) - 2*dot_k ),  dot = sequential-i FMA chain.
// Scores > 0 (Cauchy-Schwarz), so packed (bits(s)<<32 | k) unsigned-min ==
// lexicographic (s, k) min == numpy first-index argmin. Cross-gpair ties:
// strict < in ascending-k order keeps the earlier code.
__global__ __launch_bounds__(256, 2) void argmin_kernel(
    const float* __restrict__ x, const float* __restrict__ emb,
    const float* __restrict__ enorm, int* __restrict__ idx_i,
    float* __restrict__ idx_f) {
    const int l = threadIdx.x & 63;
    const int w = threadIdx.x >> 6;
    const int row_base =
        __builtin_amdgcn_readfirstlane(blockIdx.x * 256 + w * 64);

    // Prologue: lane l computes R for row (row_base + l), bit-exact np chain.
    float xl[D];
    {
        const float4* xr4 = (const float4*)(x + (size_t)(row_base + l) * D);
#pragma unroll
        for (int i = 0; i < 16; ++i) {
            float4 v = xr4[i];
            xl[4 * i + 0] = v.x;
            xl[4 * i + 1] = v.y;
            xl[4 * i + 2] = v.z;
            xl[4 * i + 3] = v.w;
        }
    }
    const float Rv = np_sumsq64(xl);

    float bestV = 3.402823466e+38f;
    int bestK = 0;

    for (int gp = 0; gp < 8; ++gp) {
        const int k0 = gp * 128 + l;
        const int k1 = k0 + 64;
        // Load + pin this lane's two embedding rows into VGPRs.
        float e0[D], e1[D];
        {
            const float4* e04 = (const float4*)(emb + ((size_t)k0 << 6));
            const float4* e14 = (const float4*)(emb + ((size_t)k1 << 6));
#pragma unroll
            for (int i = 0; i < 16; ++i) {
                float4 a = e04[i];
                float4 b = e14[i];
                e0[4 * i + 0] = vpin(a.x); e0[4 * i + 1] = vpin(a.y);
                e0[4 * i + 2] = vpin(a.z); e0[4 * i + 3] = vpin(a.w);
                e1[4 * i + 0] = vpin(b.x); e1[4 * i + 1] = vpin(b.y);
                e1[4 * i + 2] = vpin(b.z); e1[4 * i + 3] = vpin(b.w);
            }
        }
        const float n0 = enorm[k0];
        const float n1 = enorm[k1];

        for (int r = 0; r < 64; ++r) {
            // Wave-uniform address -> scalar loads into SGPRs.
            const float* __restrict__ xrow = x + (size_t)(row_base + r) * D;
            float a0 = 0.0f, a1 = 0.0f;
#pragma unroll
            for (int i = 0; i < D; ++i) {
                float xv = xrow[i];
                a0 = __builtin_fmaf(xv, e0[i], a0);
                a1 = __builtin_fmaf(xv, e1[i], a1);
            }
            float Rb = __shfl(Rv, r);
            float s0 = (Rb + n0) - 2.0f * a0;
            float s1 = (Rb + n1) - 2.0f * a1;
            // lane-local combine (k0 < k1: strict < keeps first)
            float sL = s0;
            int kL = k0;
            if (s1 < sL) { sL = s1; kL = k1; }
            // cross-lane lexicographic min via packed u64 butterfly
            unsigned long long pk =
                ((unsigned long long)__float_as_uint(sL) << 32) |
                (unsigned int)kL;
#pragma unroll
            for (int off = 1; off < 64; off <<= 1) {
                unsigned long long po = __shfl_xor(pk, off);
                pk = po < pk ? po : pk;
            }
            // row r's running best lives in lane r
            if (l == r) {
                float sm = __uint_as_float((unsigned int)(pk >> 32));
                if (sm < bestV) {
                    bestV = sm;
                    bestK = (int)(pk & 0xffffffffu);
                }
            }
        }
    }
    idx_i[row_base + l] = bestK;
    idx_f[row_base + l] = (float)bestK;
}

// ---------------- Kernel 3: gather + straight-through + loss ----------------
__global__ __launch_bounds__(256) void quant_loss_kernel(
    const float* __restrict__ x, const float* __restrict__ emb,
    const int* __restrict__ idx, float* __restrict__ out_q,
    float* __restrict__ loss_slot) {
    float lsum = 0.0f;
    for (int j = blockIdx.x * 256 + threadIdx.x; j < NELEM;
         j += QBLOCKS * 256) {
        int row = j >> 6;
        int d = j & 63;
        int k = idx[row];
        float xv = x[j];
        float ev = emb[(k << 6) + d];
        float diff = ev - xv;   // stop_gradient(quantized - inputs)
        out_q[j] = xv + diff;   // inputs + (quantized - inputs)
        lsum = __builtin_fmaf(diff, diff, lsum);
    }
#pragma unroll
    for (int o = 32; o > 0; o >>= 1) lsum += __shfl_xor(lsum, o);
    __shared__ float wsum[4];
    int wid = threadIdx.x >> 6;
    if ((threadIdx.x & 63) == 0) wsum[wid] = lsum;
    __syncthreads();
    if (threadIdx.x == 0) {
        float bsum = (wsum[0] + wsum[1]) + (wsum[2] + wsum[3]);
        // loss = (1 + commitment_cost) * mean(diff^2)
        atomicAdd(loss_slot, bsum * ((1.0f + COMMIT) / (float)NELEM));
    }
}

extern "C" void kernel_launch(void* const* d_in, const int* in_sizes, int n_in,
                              void* d_out, int out_size, void* d_ws,
                              size_t ws_size, hipStream_t stream) {
    const float* x = (const float*)d_in[0];    // [32,4096,64] f32
    const float* emb = (const float*)d_in[1];  // [1024,64] f32

    float* out = (float*)d_out;
    float* loss_slot = out;              // out[0]
    float* out_q = out + 1;              // out[1 .. 1+NELEM)
    float* idx_f = out + 1 + NELEM;      // indices as f32

    float* enorm = (float*)d_ws;                 // 4 KB
    int* idx_i = (int*)((char*)d_ws + 4096);     // 512 KB

    enorm_kernel<<<(K + 255) / 256, 256, 0, stream>>>(emb, enorm, loss_slot);
    argmin_kernel<<<NROWS / 256, 256, 0, stream>>>(x, emb, enorm, idx_i,
                                                   idx_f);
    quant_loss_kernel<<<QBLOCKS, 256, 0, stream>>>(x, emb, idx_i, out_q,
                                                   loss_slot);
}

// Round 8
// 435.149 us; speedup vs baseline: 2.5067x; 1.0696x over previous
//
#include <hip/hip_runtime.h>

#define D 64
#define K 1024
#define NROWS (32 * 4096)
#define NELEM (NROWS * D)
#define COMMIT 0.25f
#define QBLOCKS 4096

// Opaque-value fence: prevents mul+add contraction so we can reproduce
// numpy's exact f32 rounding sequence (fl(x*x) then separate adds).
static __device__ __forceinline__ float fence(float v) {
    asm("" : "+v"(v));
    return v;
}

// Volatile identity mov: cannot be sunk into loops, duplicated, or
// rematerialized -> the result MUST stay in a VGPR across the r-loop.
// (R6: empty tied asm is coalesced away. R7: non-volatile asm gets sunk
// next to its uses, defeating residency. Volatile fixes both.)
static __device__ __forceinline__ float vpin(float v) {
    float o;
    asm volatile("v_mov_b32 %0, %1" : "=v"(o) : "v"(v));
    return o;
}

// numpy pairwise_sum for n=64: 8 accumulators stride 8, sequential block
// adds, then ((r0+r1)+(r2+r3)) + ((r4+r5)+(r6+r7)).
static __device__ __forceinline__ float np_sumsq64(const float* __restrict__ e) {
    float r[8];
#pragma unroll
    for (int j = 0; j < 8; ++j) r[j] = fence(e[j] * e[j]);
#pragma unroll
    for (int t = 1; t < 8; ++t)
#pragma unroll
        for (int j = 0; j < 8; ++j) r[j] = r[j] + fence(e[8 * t + j] * e[8 * t + j]);
    return ((r[0] + r[1]) + (r[2] + r[3])) + ((r[4] + r[5]) + (r[6] + r[7]));
}

// ---------------- Kernel 1: embedding norms + zero loss slot ----------------
__global__ void enorm_kernel(const float* __restrict__ emb,
                             float* __restrict__ enorm,
                             float* __restrict__ loss_slot) {
    int k = blockIdx.x * blockDim.x + threadIdx.x;
    if (k == 0) *loss_slot = 0.0f;
    if (k < K) enorm[k] = np_sumsq64(emb + k * D);
}

// ---------------- Kernel 2: role-swapped argmin, 32 rows/wave ----------------
// Lane l owns codes {gp*128+l, gp*128+64+l}; their rows live in 128
// volatile-pinned VGPRs, loaded once per gp (8 gp = all 1024 codes). The
// x-row address is wave-uniform -> scalar s_loads feed v_fma directly.
// Score chain is bit-identical to the reference:
//   s_k = fl( fl(R + N_k) - 2*dot_k ),  dot = sequential-i FMA chain.
// Scores > 0, so u64-packed (bits(s)<<32|k) unsigned min == lexicographic
// (s,k) min == numpy first-index argmin.
__global__ __launch_bounds__(256, 2) void argmin_kernel(
    const float* __restrict__ x, const float* __restrict__ emb,
    const float* __restrict__ enorm, int* __restrict__ idx_i,
    float* __restrict__ idx_f) {
    const int l = threadIdx.x & 63;
    const int w = threadIdx.x >> 6;
    // wave owns 32 rows
    const int row_base =
        __builtin_amdgcn_readfirstlane(blockIdx.x * 128 + w * 32);

    // Prologue: lane l (and l+32, duplicate) computes R for row_base+(l&31)
    // with the bit-exact numpy pairwise chain.
    float xl[D];
    {
        const float4* xr4 =
            (const float4*)(x + (size_t)(row_base + (l & 31)) * D);
#pragma unroll
        for (int i = 0; i < 16; ++i) {
            float4 v = xr4[i];
            xl[4 * i + 0] = v.x;
            xl[4 * i + 1] = v.y;
            xl[4 * i + 2] = v.z;
            xl[4 * i + 3] = v.w;
        }
    }
    const float Rv = np_sumsq64(xl);

    unsigned long long bestPk = ~0ULL;

    for (int gp = 0; gp < 8; ++gp) {
        const int k0 = gp * 128 + l;
        const int k1 = k0 + 64;
        // Load + volatile-pin this lane's two embedding rows into VGPRs.
        float e0[D], e1[D];
        {
            const float4* e04 = (const float4*)(emb + ((size_t)k0 << 6));
            const float4* e14 = (const float4*)(emb + ((size_t)k1 << 6));
#pragma unroll
            for (int i = 0; i < 16; ++i) {
                float4 a = e04[i];
                float4 b = e14[i];
                e0[4 * i + 0] = vpin(a.x); e0[4 * i + 1] = vpin(a.y);
                e0[4 * i + 2] = vpin(a.z); e0[4 * i + 3] = vpin(a.w);
                e1[4 * i + 0] = vpin(b.x); e1[4 * i + 1] = vpin(b.y);
                e1[4 * i + 2] = vpin(b.z); e1[4 * i + 3] = vpin(b.w);
            }
        }
        const float n0 = enorm[k0];
        const float n1 = enorm[k1];

        for (int r = 0; r < 32; ++r) {
            // Wave-uniform address -> scalar loads into SGPRs.
            const float* __restrict__ xrow = x + (size_t)(row_base + r) * D;
            float a0 = 0.0f, a1 = 0.0f;
#pragma unroll
            for (int i = 0; i < D; ++i) {
                float xv = xrow[i];
                a0 = __builtin_fmaf(xv, e0[i], a0);
                a1 = __builtin_fmaf(xv, e1[i], a1);
            }
            float Rb = __shfl(Rv, r);
            float s0 = (Rb + n0) - 2.0f * a0;
            float s1 = (Rb + n1) - 2.0f * a1;
            // lane-local combine (k0 < k1: strict < keeps first index)
            float sL = s0;
            int kL = k0;
            if (s1 < sL) { sL = s1; kL = k1; }
            // cross-lane lexicographic min via packed u64 butterfly
            unsigned long long pk =
                ((unsigned long long)__float_as_uint(sL) << 32) |
                (unsigned int)kL;
#pragma unroll
            for (int off = 1; off < 64; off <<= 1) {
                unsigned long long po = __shfl_xor(pk, off);
                pk = po < pk ? po : pk;
            }
            // row r's running best lives in lane r
            if (l == r) bestPk = pk < bestPk ? pk : bestPk;
        }
    }
    if (l < 32) {
        int bk = (int)(bestPk & 0xffffffffu);
        idx_i[row_base + l] = bk;
        idx_f[row_base + l] = (float)bk;
    }
}

// ---------------- Kernel 3: gather + straight-through + loss ----------------
__global__ __launch_bounds__(256) void quant_loss_kernel(
    const float* __restrict__ x, const float* __restrict__ emb,
    const int* __restrict__ idx, float* __restrict__ out_q,
    float* __restrict__ loss_slot) {
    float lsum = 0.0f;
    for (int j = blockIdx.x * 256 + threadIdx.x; j < NELEM;
         j += QBLOCKS * 256) {
        int row = j >> 6;
        int d = j & 63;
        int k = idx[row];
        float xv = x[j];
        float ev = emb[(k << 6) + d];
        float diff = ev - xv;   // stop_gradient(quantized - inputs)
        out_q[j] = xv + diff;   // inputs + (quantized - inputs)
        lsum = __builtin_fmaf(diff, diff, lsum);
    }
#pragma unroll
    for (int o = 32; o > 0; o >>= 1) lsum += __shfl_xor(lsum, o);
    __shared__ float wsum[4];
    int wid = threadIdx.x >> 6;
    if ((threadIdx.x & 63) == 0) wsum[wid] = lsum;
    __syncthreads();
    if (threadIdx.x == 0) {
        float bsum = (wsum[0] + wsum[1]) + (wsum[2] + wsum[3]);
        // loss = (1 + commitment_cost) * mean(diff^2)
        atomicAdd(loss_slot, bsum * ((1.0f + COMMIT) / (float)NELEM));
    }
}

extern "C" void kernel_launch(void* const* d_in, const int* in_sizes, int n_in,
                              void* d_out, int out_size, void* d_ws,
                              size_t ws_size, hipStream_t stream) {
    const float* x = (const float*)d_in[0];    // [32,4096,64] f32
    const float* emb = (const float*)d_in[1];  // [1024,64] f32

    float* out = (float*)d_out;
    float* loss_slot = out;              // out[0]
    float* out_q = out + 1;              // out[1 .. 1+NELEM)
    float* idx_f = out + 1 + NELEM;      // indices as f32

    float* enorm = (float*)d_ws;                 // 4 KB
    int* idx_i = (int*)((char*)d_ws + 4096);     // 512 KB

    enorm_kernel<<<(K + 255) / 256, 256, 0, stream>>>(emb, enorm, loss_slot);
    argmin_kernel<<<NROWS / 128, 256, 0, stream>>>(x, emb, enorm, idx_i,
                                                   idx_f);
    quant_loss_kernel<<<QBLOCKS, 256, 0, stream>>>(x, emb, idx_i, out_q,
                                                   loss_slot);
}